// Round 1
// baseline (2683.392 us; speedup 1.0000x reference)
//
#include <hip/hip_runtime.h>
#include <math.h>

// Problem dims
#define DB 4
#define DH 64
#define DW 64
#define DL 32
#define DC 128
#define KM 32   // kept h,w modes
#define LF 8    // kept l modes
#define NB 8
#define BS 16

// ws float offsets
#define OFF_W1R 0
#define OFF_W1I 2048
#define OFF_W2R 4096
#define OFF_W2I 6144
#define OFF_BR1 8192
#define OFF_BI1 8320
#define OFF_BR2 8448
#define OFF_BI2 8576
#define OFF_TW64 8704   // 64 float2 (cos,sin of +2*pi*t/64)
#define OFF_TW32 8832   // 32 float2 (cos,sin of +2*pi*t/32)
#define OFF_XW  16384          // float2 [4][64][32][8][128]  (later reused as U [4][32][64][8][128])
#define OFF_XS  16793600       // float2 [4][32][32][8][128]
#define WS_FLOATS_NEEDED 25182208ull

#define SCALE_FW1 0.02209708691207961f   // 1/(8*sqrt(32))
#define SCALE_8   0.125f

static __device__ __forceinline__ int rfl(int v) { return __builtin_amdgcn_readfirstlane(v); }

// ---------------------------------------------------------------------------
// K0: fold LoRA into effective weights, build bias combos and twiddle tables.
// Weff[k][i][o] = w[k][i][o] + (1/32) * sum_r A[k][i][r] * (sum_e ew[e]*B[k][e][r][o])
__global__ __launch_bounds__(256) void prep_kernel(
    const float* __restrict__ w1, const float* __restrict__ b1,
    const float* __restrict__ w2, const float* __restrict__ b2,
    const float* __restrict__ A1r, const float* __restrict__ B1r,
    const float* __restrict__ A1i, const float* __restrict__ B1i,
    const float* __restrict__ A2r, const float* __restrict__ B2r,
    const float* __restrict__ A2i, const float* __restrict__ B2i,
    const float* __restrict__ ew, float* __restrict__ ws) {
  int tid = threadIdx.x;
  float e0 = ew[0], e1 = ew[1], e2 = ew[2], e3 = ew[3];
  const float* Ws[4] = {w1, w1 + 2048, w2, w2 + 2048};
  const float* As[4] = {A1r, A1i, A2r, A2i};
  const float* Bs[4] = {B1r, B1i, B2r, B2i};
  for (int cfg = 0; cfg < 4; cfg++) {
    float* dst = ws + cfg * 2048;
    const float* A0 = As[cfg];
    const float* B0 = Bs[cfg];
    const float* W0 = Ws[cfg];
    for (int e = tid; e < 2048; e += 256) {
      int k = e >> 8, i = (e >> 4) & 15, o = e & 15;
      const float* A = A0 + k * 512 + i * 32;   // [k][i][r]
      const float* Bp = B0 + k * 2048 + o;      // [k][e][r][o]
      float acc = 0.f;
      for (int r = 0; r < 32; r++) {
        float bm = e0 * Bp[r * 16] + e1 * Bp[512 + r * 16] +
                   e2 * Bp[1024 + r * 16] + e3 * Bp[1536 + r * 16];
        acc += A[r] * bm;
      }
      dst[e] = W0[k * 256 + i * 16 + o] + (1.0f / 32.0f) * acc;
    }
  }
  if (tid < 128) {
    ws[OFF_BR1 + tid] = b1[tid] - b1[128 + tid];
    ws[OFF_BI1 + tid] = b1[tid] + b1[128 + tid];
    ws[OFF_BR2 + tid] = b2[tid] - b2[128 + tid];
    ws[OFF_BI2 + tid] = b2[tid] + b2[128 + tid];
  }
  if (tid < 64) {
    float s, c;
    sincospif(2.0f * (float)tid / 64.0f, &s, &c);
    ws[OFF_TW64 + 2 * tid] = c;
    ws[OFF_TW64 + 2 * tid + 1] = s;
  }
  if (tid < 32) {
    float s, c;
    sincospif(2.0f * (float)tid / 32.0f, &s, &c);
    ws[OFF_TW32 + 2 * tid] = c;
    ws[OFF_TW32 + 2 * tid + 1] = s;
  }
}

// ---------------------------------------------------------------------------
// K12: fused forward L-DFT (p:32 -> l:8) and W-DFT (n:64 -> w:32).
// Block handles (b, m, ctile of 16 channels). Out: xw[b][m][w][l][c] (float2).
__global__ __launch_bounds__(256) void fwd_lw_kernel(
    const float* __restrict__ x, const float* __restrict__ ws,
    float2* __restrict__ xw) {
  __shared__ float2 xl[64][8][17];   // [n][l][c+pad] : 69.6 KB
  const float2* tw64 = (const float2*)(ws + OFF_TW64);
  const float2* tw32 = (const float2*)(ws + OFF_TW32);

  int bid = blockIdx.x;
  int ct = bid & 7;
  int m = (bid >> 3) & 63;
  int b = bid >> 9;
  int c0 = ct * 16;
  int tid = threadIdx.x;

  // Stage 1: per (n, c) line, reduce p(32) -> l(8) with e^{-2pi i l p/32}
  {
    int cl = tid & 15, n0 = tid >> 4;
    const float* xb = x + ((size_t)(b * 64 + m)) * (64 * 32 * 128) + c0 + cl;
    for (int jj = 0; jj < 4; jj++) {
      int n = n0 + 16 * jj;
      const float* xp = xb + n * (32 * 128);
      float ar[8] = {0, 0, 0, 0, 0, 0, 0, 0};
      float ai[8] = {0, 0, 0, 0, 0, 0, 0, 0};
      for (int p = 0; p < 32; p++) {
        float xv = xp[p * 128];
#pragma unroll
        for (int l = 0; l < 8; l++) {
          float2 t = tw32[(l * p) & 31];
          ar[l] += xv * t.x;
          ai[l] -= xv * t.y;
        }
      }
#pragma unroll
      for (int l = 0; l < 8; l++) xl[n][l][cl] = make_float2(ar[l], ai[l]);
    }
  }
  __syncthreads();

  // Stage 2: reduce n(64) -> w(32) with e^{-2pi i w n/64}; each thread: 16 w's.
  {
    int cl = tid & 15;
    int l = (tid >> 4) & 7;
    int w0 = rfl(tid >> 7);  // 0..1, wave-uniform
    float accr[16] = {0}, acci[16] = {0};
    for (int n = 0; n < 64; n++) {
      float2 v = xl[n][l][cl];
#pragma unroll
      for (int j = 0; j < 16; j++) {
        int wv = w0 * 16 + j;
        float2 t = tw64[(wv * n) & 63];
        accr[j] += v.x * t.x + v.y * t.y;
        acci[j] += v.y * t.x - v.x * t.y;
      }
    }
    float2* xwb = xw + ((size_t)(b * 64 + m)) * (32 * 8 * 128) + l * 128 + c0 + cl;
#pragma unroll
    for (int j = 0; j < 16; j++) {
      int wv = w0 * 16 + j;
      xwb[(size_t)wv * (8 * 128)] =
          make_float2(accr[j] * SCALE_FW1, acci[j] * SCALE_FW1);
    }
  }
}

// ---------------------------------------------------------------------------
// K3: forward H-DFT (m:64 -> h:32). xs[b][h][w][l][c] = (1/8) sum_m xw * e^{-2pi i h m/64}
__global__ __launch_bounds__(256) void fwd_h_kernel(
    const float* __restrict__ ws, const float2* __restrict__ xw,
    float2* __restrict__ xs) {
  const float2* tw64 = (const float2*)(ws + OFF_TW64);
  int gid = blockIdx.x * 256 + threadIdx.x;
  int c = gid & 127;
  int l = rfl((gid >> 7) & 7);
  int w = rfl((gid >> 10) & 31);
  int hh = rfl((gid >> 15) & 1);
  int b = rfl(gid >> 16);

  const float2* src = xw + (size_t)b * (64 * 32 * 8 * 128) + ((size_t)w * 8 + l) * 128 + c;
  float ar[16] = {0}, ai[16] = {0};
  for (int mm = 0; mm < 64; mm++) {
    float2 v = src[(size_t)mm * (32 * 8 * 128)];
#pragma unroll
    for (int t = 0; t < 16; t++) {
      int h = hh * 16 + t;
      float2 tw = tw64[(h * mm) & 63];
      ar[t] += v.x * tw.x + v.y * tw.y;
      ai[t] += v.y * tw.x - v.x * tw.y;
    }
  }
  float2* dst = xs + (((size_t)(b * 32 + hh * 16) * 32 + w) * 8 + l) * 128 + c;
#pragma unroll
  for (int t = 0; t < 16; t++)
    dst[(size_t)t * (32 * 8 * 128)] = make_float2(ar[t] * SCALE_8, ai[t] * SCALE_8);
}

// ---------------------------------------------------------------------------
// K4: MLP at kept modes, in place on xs. One thread per (site, block k).
__global__ __launch_bounds__(256) void mlp_kernel(const float* __restrict__ ws,
                                                  float2* __restrict__ xs) {
  __shared__ float Wsh[4][8][260];
  __shared__ float Bsh[4][8][17];
  int tid = threadIdx.x;
  for (int q = tid; q < 4 * 2048; q += 256) {
    int cfg = q >> 11, e = q & 2047;
    Wsh[cfg][e >> 8][e & 255] = ws[cfg * 2048 + e];
  }
  for (int q = tid; q < 4 * 128; q += 256) {
    int cfg = q >> 7, e = q & 127;
    Bsh[cfg][e >> 4][e & 15] = ws[OFF_BR1 + cfg * 128 + e];
  }
  __syncthreads();

  int gid = blockIdx.x * 256 + tid;
  int k = gid & 7;
  size_t site = (size_t)(gid >> 3);
  float2* vp = xs + site * 128 + k * 16;

  float vr[16], vi[16];
#pragma unroll
  for (int i = 0; i < 16; i++) { float2 t = vp[i]; vr[i] = t.x; vi[i] = t.y; }

  float ar[16], ai[16];
#pragma unroll
  for (int o = 0; o < 16; o++) { ar[o] = Bsh[0][k][o]; ai[o] = Bsh[1][k][o]; }
  for (int i = 0; i < 16; i++) {
    const float* wr = &Wsh[0][k][i * 16];
    const float* wi = &Wsh[1][k][i * 16];
    float xr = vr[i], xi = vi[i];
#pragma unroll
    for (int o = 0; o < 16; o++) {
      ar[o] += xr * wr[o] - xi * wi[o];
      ai[o] += xi * wr[o] + xr * wi[o];
    }
  }
  // exact GELU on real and imag separately
#pragma unroll
  for (int o = 0; o < 16; o++) {
    float a = ar[o], c = ai[o];
    vr[o] = 0.5f * a * (1.0f + erff(a * 0.70710678118654752f));
    vi[o] = 0.5f * c * (1.0f + erff(c * 0.70710678118654752f));
  }
  // layer 2
#pragma unroll
  for (int o = 0; o < 16; o++) { ar[o] = Bsh[2][k][o]; ai[o] = Bsh[3][k][o]; }
  for (int i = 0; i < 16; i++) {
    const float* wr = &Wsh[2][k][i * 16];
    const float* wi = &Wsh[3][k][i * 16];
    float xr = vr[i], xi = vi[i];
#pragma unroll
    for (int o = 0; o < 16; o++) {
      ar[o] += xr * wr[o] - xi * wi[o];
      ai[o] += xi * wr[o] + xr * wi[o];
    }
  }
#pragma unroll
  for (int o = 0; o < 16; o++) vp[o] = make_float2(ar[o], ai[o]);
}

// ---------------------------------------------------------------------------
// K5: inverse W-DFT (w:32 kept -> n:64). u[b][h][n][l][c] = (1/8) sum_w xs * e^{+2pi i w n/64}
__global__ __launch_bounds__(256) void inv_n_kernel(const float* __restrict__ ws,
                                                    const float2* __restrict__ xs,
                                                    float2* __restrict__ u) {
  const float2* tw64 = (const float2*)(ws + OFF_TW64);
  int gid = blockIdx.x * 256 + threadIdx.x;
  int c = gid & 127;
  int l = rfl((gid >> 7) & 7);
  int nh = rfl((gid >> 10) & 1);
  int h = rfl((gid >> 11) & 31);
  int b = rfl(gid >> 16);

  const float2* src = xs + ((size_t)(b * 32 + h) * 32) * (8 * 128) + l * 128 + c;
  float ar[32] = {0}, ai[32] = {0};
  for (int w = 0; w < 32; w++) {
    float2 v = src[(size_t)w * (8 * 128)];
#pragma unroll
    for (int j = 0; j < 32; j++) {
      int n = nh * 32 + j;
      float2 t = tw64[(w * n) & 63];
      ar[j] += v.x * t.x - v.y * t.y;
      ai[j] += v.y * t.x + v.x * t.y;
    }
  }
  float2* dst = u + (size_t)(b * 32 + h) * (64 * 8 * 128) +
                (size_t)(nh * 32) * (8 * 128) + l * 128 + c;
#pragma unroll
  for (int j = 0; j < 32; j++)
    dst[(size_t)j * (8 * 128)] = make_float2(ar[j] * SCALE_8, ai[j] * SCALE_8);
}

// ---------------------------------------------------------------------------
// K67: fused inverse H-DFT (h:32 -> m:64) + l-irfft (l:8 -> p:32) + add x.
// Block handles (b, n, ctile of 16). out real.
__global__ __launch_bounds__(256) void inv_final_kernel(
    const float* __restrict__ x, const float* __restrict__ ws,
    const float2* __restrict__ u, float* __restrict__ out) {
  __shared__ float2 ush[32][16][9];  // [h][c][l+pad] : 36.9 KB
  const float2* tw64 = (const float2*)(ws + OFF_TW64);
  const float2* tw32 = (const float2*)(ws + OFF_TW32);

  int bid = blockIdx.x;
  int ct = bid & 7;
  int n = (bid >> 3) & 63;
  int b = bid >> 9;
  int c0 = ct * 16;
  int tid = threadIdx.x;

  for (int q = tid; q < 4096; q += 256) {
    int cc = q & 15, l = (q >> 4) & 7, h = q >> 7;
    ush[h][cc][l] =
        u[(((size_t)(b * 32 + h)) * 64 + n) * (8 * 128) + l * 128 + c0 + cc];
  }
  __syncthreads();

  int cc = tid & 15;
  int m0 = tid >> 4;  // 0..15
  const float f0 = SCALE_FW1;  // (1/8)*(1/sqrt(32))
  for (int jm = 0; jm < 4; jm++) {
    int m = m0 + 16 * jm;
    float tr[8] = {0}, ti[8] = {0};
    for (int h = 0; h < 32; h++) {
      float2 t = tw64[(h * m) & 63];  // lane-varying in m; small table, L1-hot
      float2 uv[8];
#pragma unroll
      for (int l = 0; l < 8; l++) uv[l] = ush[h][cc][l];
#pragma unroll
      for (int l = 0; l < 8; l++) {
        tr[l] += uv[l].x * t.x - uv[l].y * t.y;
        ti[l] += uv[l].y * t.x + uv[l].x * t.y;
      }
    }
#pragma unroll
    for (int l = 0; l < 8; l++) {
      float f = (l == 0) ? f0 : 2.0f * f0;
      tr[l] *= f;
      ti[l] *= f;
    }
    const float* xp = x + ((((size_t)(b * 64 + m)) * 64 + n) * 32) * 128 + c0 + cc;
    float* op = out + ((((size_t)(b * 64 + m)) * 64 + n) * 32) * 128 + c0 + cc;
    for (int p = 0; p < 32; p++) {
      float s = 0.f;
#pragma unroll
      for (int l = 0; l < 8; l++) {
        float2 t = tw32[(l * p) & 31];
        s += tr[l] * t.x - ti[l] * t.y;
      }
      op[(size_t)p * 128] = xp[(size_t)p * 128] + s;
    }
  }
}

// ---------------------------------------------------------------------------
extern "C" void kernel_launch(void* const* d_in, const int* in_sizes, int n_in,
                              void* d_out, int out_size, void* d_ws, size_t ws_size,
                              hipStream_t stream) {
  const float* x   = (const float*)d_in[0];
  const float* w1  = (const float*)d_in[1];
  const float* b1  = (const float*)d_in[2];
  const float* w2  = (const float*)d_in[3];
  const float* b2  = (const float*)d_in[4];
  const float* A1r = (const float*)d_in[5];
  const float* B1r = (const float*)d_in[6];
  const float* A1i = (const float*)d_in[7];
  const float* B1i = (const float*)d_in[8];
  const float* A2r = (const float*)d_in[9];
  const float* B2r = (const float*)d_in[10];
  const float* A2i = (const float*)d_in[11];
  const float* B2i = (const float*)d_in[12];
  const float* ew  = (const float*)d_in[13];
  float* out = (float*)d_out;
  float* ws = (float*)d_ws;

  if (ws_size < WS_FLOATS_NEEDED * sizeof(float)) return;  // need ~101 MB scratch

  float2* xw = (float2*)(ws + OFF_XW);   // also reused as U after K4
  float2* xs = (float2*)(ws + OFF_XS);

  hipLaunchKernelGGL(prep_kernel, dim3(1), dim3(256), 0, stream,
                     w1, b1, w2, b2, A1r, B1r, A1i, B1i, A2r, B2r, A2i, B2i, ew, ws);
  hipLaunchKernelGGL(fwd_lw_kernel, dim3(4 * 64 * 8), dim3(256), 0, stream, x, ws, xw);
  hipLaunchKernelGGL(fwd_h_kernel, dim3(1024), dim3(256), 0, stream, ws, xw, xs);
  hipLaunchKernelGGL(mlp_kernel, dim3(1024), dim3(256), 0, stream, ws, xs);
  hipLaunchKernelGGL(inv_n_kernel, dim3(1024), dim3(256), 0, stream, ws, xs, xw);
  hipLaunchKernelGGL(inv_final_kernel, dim3(4 * 64 * 8), dim3(256), 0, stream, x, ws, xw, out);
}